// Round 2
// baseline (46.391 us; speedup 1.0000x reference)
//
#include <hip/hip_runtime.h>
#include <math.h>

// Problem dims (fixed by reference setup_inputs)
#define BB 32
#define LL 8192
#define DD 256
#define QQ 512
#define HH 256
#define MM 5
#define PRUNE_LEFT  (-50)
#define PRUNE_RIGHT (50)

__device__ inline float wave_reduce_add(float v) {
    #pragma unroll
    for (int m = 1; m < 64; m <<= 1)
        v += __shfl_xor(v, m, 64);
    return v;
}

// One block per batch. 256 threads = 4 waves.
// Phase 1 : proj = tanh(W1 @ q + b1)      (lane-split-Q, coalesced W1)
// Phase 1b: stats = exp(W2 @ proj + b2)   (alpha | beta | kappa)
// Phase 2 : dense p_ctx[b, :]             (exact reference math + prune mask)
// Phase 3 : expected[b, :] over the exact nonzero window, 256-row chunks
__global__ void __launch_bounds__(256, 1) k_fused(
    const float* __restrict__ ctx,
    const float* __restrict__ query,
    const float* __restrict__ W1,
    const float* __restrict__ b1,
    const float* __restrict__ W2,
    const float* __restrict__ b2,
    float* __restrict__ expected,
    float* __restrict__ p_ctx)
{
    __shared__ float s_proj[HH];
    __shared__ float s_stats[3 * MM];
    __shared__ float s_pwin[256];
    __shared__ int s_lo, s_hi;

    const int b    = blockIdx.x;
    const int t    = threadIdx.x;
    const int lane = t & 63;
    const int w    = t >> 6;   // wave id 0..3

    // ---- Phase 1: proj = tanh(W1 @ q + b1), wave w owns rows [w*64, w*64+64) ----
    const float4* q4 = (const float4*)(query + (size_t)b * QQ);  // 128 float4
    const float4 qa = q4[lane];
    const float4 qb = q4[64 + lane];
    const float4* W1_4 = (const float4*)W1;   // row h starts at h*128
    for (int r = 0; r < 64; ++r) {
        const int h = w * 64 + r;
        const float4 wa = W1_4[(size_t)h * 128 + lane];
        const float4 wb = W1_4[(size_t)h * 128 + 64 + lane];
        float acc = wa.x * qa.x + wa.y * qa.y + wa.z * qa.z + wa.w * qa.w
                  + wb.x * qb.x + wb.y * qb.y + wb.z * qb.z + wb.w * qb.w;
        acc = wave_reduce_add(acc);
        if (lane == 0) s_proj[h] = tanhf(acc + b1[h]);
    }
    __syncthreads();

    // ---- Phase 1b: stats = exp(W2 @ proj + b2), 15 rows across 4 waves ----
    const float4* W2_4 = (const float4*)W2;          // row j starts at j*64
    const float4  pv   = ((const float4*)s_proj)[lane];
    for (int j = w; j < 3 * MM; j += 4) {
        const float4 w2 = W2_4[(size_t)j * 64 + lane];
        float acc = w2.x * pv.x + w2.y * pv.y + w2.z * pv.z + w2.w * pv.w;
        acc = wave_reduce_add(acc);
        if (lane == 0) s_stats[j] = expf(acc + b2[j]);
    }
    __syncthreads();

    // ---- Window bounds (union of per-mixture prune windows, clamped) ----
    if (t == 0) {
        float cmin = 1e30f, cmax = -1e30f;
        #pragma unroll
        for (int m = 0; m < MM; ++m) {
            const float c = rintf(s_stats[2 * MM + m]);   // round-half-even = jnp.round
            cmin = fminf(cmin, c);
            cmax = fmaxf(cmax, c);
        }
        const float lof = fmaxf(0.f, cmin + (float)PRUNE_LEFT);
        const float hif = fminf((float)LL, cmax + (float)(PRUNE_RIGHT + 1));
        int lo = (lof >= (float)LL) ? LL : (int)lof;
        int hi = (hif <= 0.f) ? 0 : (int)hif;
        if (hi < lo) hi = lo;
        s_lo = lo;
        s_hi = hi;
    }
    __syncthreads();

    float alpha[MM], beta[MM], kappa[MM], cen[MM];
    #pragma unroll
    for (int m = 0; m < MM; ++m) {
        alpha[m] = s_stats[m];
        beta[m]  = s_stats[MM + m];
        kappa[m] = s_stats[2 * MM + m];
        cen[m]   = rintf(kappa[m]);
    }
    const int lo = s_lo, hi = s_hi;

    // ---- Phase 2: dense p_ctx for this batch (exact reference math) ----
    float* pb = p_ctx + (size_t)b * LL;
    for (int l = t; l < LL; l += 256) {
        const float pos = (float)l;
        float p = 0.f;
        #pragma unroll
        for (int m = 0; m < MM; ++m) {
            if (pos >= cen[m] + (float)PRUNE_LEFT && pos < cen[m] + (float)(PRUNE_RIGHT + 1)) {
                const float diff = pos - kappa[m];
                p += alpha[m] * expf(-beta[m] * diff * diff);
            }
        }
        pb[l] = p;
    }

    // ---- Phase 3: expected[b, t] over the window, 256-row chunks ----
    float acc = 0.f;
    const float* cb = ctx + (size_t)b * LL * DD;
    for (int base = lo; base < hi; base += 256) {
        const int n = min(256, hi - base);
        __syncthreads();
        if (t < n) {
            const float pos = (float)(base + t);
            float p = 0.f;
            #pragma unroll
            for (int m = 0; m < MM; ++m) {
                if (pos >= cen[m] + (float)PRUNE_LEFT && pos < cen[m] + (float)(PRUNE_RIGHT + 1)) {
                    const float diff = pos - kappa[m];
                    p += alpha[m] * expf(-beta[m] * diff * diff);
                }
            }
            s_pwin[t] = p;
        }
        __syncthreads();
        for (int i = 0; i < n; ++i) {
            acc += s_pwin[i] * cb[(size_t)(base + i) * DD + t];   // coalesced 1 KiB/row
        }
    }
    expected[(size_t)b * DD + t] = acc;
}

extern "C" void kernel_launch(void* const* d_in, const int* in_sizes, int n_in,
                              void* d_out, int out_size, void* d_ws, size_t ws_size,
                              hipStream_t stream) {
    const float* ctx   = (const float*)d_in[0];
    const float* query = (const float*)d_in[1];
    const float* W1    = (const float*)d_in[2];
    const float* b1    = (const float*)d_in[3];
    const float* W2    = (const float*)d_in[4];
    const float* b2    = (const float*)d_in[5];

    float* out      = (float*)d_out;
    float* expected = out;             // (B, D)  = 8192 floats
    float* p_ctx    = out + BB * DD;   // (B, L)  = 262144 floats

    k_fused<<<BB, 256, 0, stream>>>(ctx, query, W1, b1, W2, b2, expected, p_ctx);
}

// Round 3
// 18.806 us; speedup vs baseline: 2.4668x; 2.4668x over previous
//
#include <hip/hip_runtime.h>
#include <math.h>

// Problem dims (fixed by reference setup_inputs)
#define BB 32
#define LL 8192
#define DD 256
#define QQ 512
#define HH 256
#define MM 5
#define PRUNE_LEFT  (-50)
#define PRUNE_RIGHT (50)

__device__ inline float wave_reduce_add(float v) {
    #pragma unroll
    for (int m = 1; m < 64; m <<= 1)
        v += __shfl_xor(v, m, 64);
    return v;
}

// Kernel 1: per-batch MLP -> exp(stats). 32 blocks x 1024 threads (16 waves).
// Wave w computes proj rows [w*16, w*16+16) (statically unrolled -> 16
// independent load+reduce chains); then wave j (j<15) computes stats row j.
__global__ void __launch_bounds__(1024) k_stats(const float* __restrict__ query,
                                                const float* __restrict__ W1,
                                                const float* __restrict__ b1,
                                                const float* __restrict__ W2,
                                                const float* __restrict__ b2,
                                                float* __restrict__ stats_out) {
    __shared__ float s_proj[HH];
    const int b    = blockIdx.x;
    const int t    = threadIdx.x;
    const int lane = t & 63;
    const int w    = t >> 6;   // 0..15

    const float4* q4 = (const float4*)(query + (size_t)b * QQ);  // 128 float4
    const float4 qa = q4[lane];
    const float4 qb = q4[64 + lane];
    const float4* W1_4 = (const float4*)W1;   // row h = 128 float4

    #pragma unroll
    for (int r = 0; r < 16; ++r) {
        const int h = w * 16 + r;
        const float4 wa = W1_4[(size_t)h * 128 + lane];
        const float4 wb = W1_4[(size_t)h * 128 + 64 + lane];
        float acc = wa.x * qa.x + wa.y * qa.y + wa.z * qa.z + wa.w * qa.w
                  + wb.x * qb.x + wb.y * qb.y + wb.z * qb.z + wb.w * qb.w;
        acc = wave_reduce_add(acc);
        if (lane == 0) s_proj[h] = tanhf(acc + b1[h]);
    }
    __syncthreads();

    if (w < 3 * MM) {   // 15 rows, one per wave, all parallel
        const float4 pv = ((const float4*)s_proj)[lane];
        const float4 w2 = ((const float4*)W2)[(size_t)w * 64 + lane];
        float acc = w2.x * pv.x + w2.y * pv.y + w2.z * pv.z + w2.w * pv.w;
        acc = wave_reduce_add(acc);
        if (lane == 0) stats_out[b * (3 * MM) + w] = expf(acc + b2[w]);
    }
}

// Kernel 2: grid (9, 32) x 1024 threads.
//   blockIdx.x = s < 8 : dense p_ctx slice [s*1024, s*1024+1024) for batch b
//   blockIdx.x = 8     : expected[b, :] over the exact nonzero window,
//                        rows interleaved 4-ways across wave-quarters.
__global__ void __launch_bounds__(1024) k_main(const float* __restrict__ ctx,
                                               const float* __restrict__ stats,
                                               float* __restrict__ p_ctx,
                                               float* __restrict__ expected) {
    const int b = blockIdx.y;
    const int s = blockIdx.x;
    const int t = threadIdx.x;

    const float* st = stats + b * (3 * MM);
    float alpha[MM], beta[MM], kappa[MM], cen[MM];
    #pragma unroll
    for (int m = 0; m < MM; ++m) {
        alpha[m] = st[m];
        beta[m]  = st[MM + m];
        kappa[m] = st[2 * MM + m];
        cen[m]   = rintf(kappa[m]);   // round-half-even = jnp.round
    }

    if (s < 8) {
        // ---- dense p_ctx (exact reference math incl. prune mask) ----
        const int l = s * 1024 + t;
        const float pos = (float)l;
        float p = 0.f;
        #pragma unroll
        for (int m = 0; m < MM; ++m) {
            if (pos >= cen[m] + (float)PRUNE_LEFT && pos < cen[m] + (float)(PRUNE_RIGHT + 1)) {
                const float diff = pos - kappa[m];
                p += alpha[m] * expf(-beta[m] * diff * diff);
            }
        }
        p_ctx[(size_t)b * LL + l] = p;
        return;
    }

    // ---- expected[b, :] ----
    __shared__ float s_pwin[1024];
    __shared__ float s_part[4][DD];

    float cmin = 1e30f, cmax = -1e30f;
    #pragma unroll
    for (int m = 0; m < MM; ++m) {
        cmin = fminf(cmin, cen[m]);
        cmax = fmaxf(cmax, cen[m]);
    }
    float lof = fminf(fmaxf(0.f, cmin + (float)PRUNE_LEFT), (float)LL);
    float hif = fminf(fmaxf(0.f, cmax + (float)(PRUNE_RIGHT + 1)), (float)LL);
    int lo = (int)lof;
    int hi = (int)hif;
    if (hi < lo) hi = lo;

    const int d  = t & 255;   // output column
    const int wq = t >> 8;    // row-quarter 0..3
    const float* cb = ctx + (size_t)b * LL * DD;

    float acc = 0.f;
    for (int base = lo; base < hi; base += 1024) {
        const int n = min(1024, hi - base);
        __syncthreads();
        if (t < n) {
            const float pos = (float)(base + t);
            float p = 0.f;
            #pragma unroll
            for (int m = 0; m < MM; ++m) {
                if (pos >= cen[m] + (float)PRUNE_LEFT && pos < cen[m] + (float)(PRUNE_RIGHT + 1)) {
                    const float diff = pos - kappa[m];
                    p += alpha[m] * expf(-beta[m] * diff * diff);
                }
            }
            s_pwin[t] = p;
        }
        __syncthreads();
        #pragma unroll 4
        for (int r = wq; r < n; r += 4) {
            acc += s_pwin[r] * cb[(size_t)(base + r) * DD + d];   // coalesced
        }
    }
    s_part[wq][d] = acc;
    __syncthreads();
    if (t < DD) {
        expected[(size_t)b * DD + t] =
            s_part[0][t] + s_part[1][t] + s_part[2][t] + s_part[3][t];
    }
}

extern "C" void kernel_launch(void* const* d_in, const int* in_sizes, int n_in,
                              void* d_out, int out_size, void* d_ws, size_t ws_size,
                              hipStream_t stream) {
    const float* ctx   = (const float*)d_in[0];
    const float* query = (const float*)d_in[1];
    const float* W1    = (const float*)d_in[2];
    const float* b1    = (const float*)d_in[3];
    const float* W2    = (const float*)d_in[4];
    const float* b2    = (const float*)d_in[5];

    float* out      = (float*)d_out;
    float* expected = out;             // (B, D)  = 8192 floats
    float* p_ctx    = out + BB * DD;   // (B, L)  = 262144 floats
    float* stats    = (float*)d_ws;    // (B, 15) = exp(stats), alpha|beta|kappa

    k_stats<<<BB, 1024, 0, stream>>>(query, W1, b1, W2, b2, stats);

    dim3 g2(9, BB);
    k_main<<<g2, 1024, 0, stream>>>(ctx, stats, p_ctx, expected);
}

// Round 4
// 17.873 us; speedup vs baseline: 2.5956x; 1.0522x over previous
//
#include <hip/hip_runtime.h>
#include <math.h>

// Problem dims (fixed by reference setup_inputs)
#define BB 32
#define LL 8192
#define DD 256
#define QQ 512
#define HH 256
#define MM 5
#define PRUNE_LEFT  (-50)
#define PRUNE_RIGHT (50)

__device__ inline float wave_reduce_add(float v) {
    #pragma unroll
    for (int m = 1; m < 64; m <<= 1)
        v += __shfl_xor(v, m, 64);
    return v;
}

// One block per batch, 1024 threads (16 waves, 4/SIMD).
// Phase 1 : proj = tanh(W1 @ q + b1)   — wave w owns 16 rows, statically
//           unrolled -> 16 independent coalesced-load+reduce chains.
// Phase 1b: stats = exp(W2 @ proj + b2) — one row per wave, 15 waves parallel.
// Phase 2 : dense p_ctx[b,:] (exact reference math incl. prune mask),
//           mirrored into LDS for phase 3.
// Phase 3 : expected[b,:] over the exact nonzero window; rows interleaved
//           4-way across wave-quarters (unroll 4 -> deep load pipeline).
__global__ void __launch_bounds__(1024, 1) k_fused(
    const float* __restrict__ ctx,
    const float* __restrict__ query,
    const float* __restrict__ W1,
    const float* __restrict__ b1,
    const float* __restrict__ W2,
    const float* __restrict__ b2,
    float* __restrict__ expected,
    float* __restrict__ p_ctx)
{
    __shared__ float s_proj[HH];
    __shared__ float s_stats[3 * MM];
    __shared__ float s_p[LL];          // 32 KB: this batch's p_ctx
    __shared__ float s_part[4][DD];

    const int b    = blockIdx.x;
    const int t    = threadIdx.x;
    const int lane = t & 63;
    const int w    = t >> 6;   // wave id 0..15

    // ---- Phase 1: proj = tanh(W1 @ q + b1) ----
    const float4* q4 = (const float4*)(query + (size_t)b * QQ);  // 128 float4
    const float4 qa = q4[lane];
    const float4 qb = q4[64 + lane];
    const float4* W1_4 = (const float4*)W1;   // row h = 128 float4

    #pragma unroll
    for (int r = 0; r < 16; ++r) {
        const int h = w * 16 + r;
        const float4 wa = W1_4[(size_t)h * 128 + lane];
        const float4 wb = W1_4[(size_t)h * 128 + 64 + lane];
        float acc = wa.x * qa.x + wa.y * qa.y + wa.z * qa.z + wa.w * qa.w
                  + wb.x * qb.x + wb.y * qb.y + wb.z * qb.z + wb.w * qb.w;
        acc = wave_reduce_add(acc);
        if (lane == 0) s_proj[h] = tanhf(acc + b1[h]);
    }
    __syncthreads();

    // ---- Phase 1b: stats = exp(W2 @ proj + b2), one row per wave ----
    if (w < 3 * MM) {
        const float4 pv = ((const float4*)s_proj)[lane];
        const float4 w2 = ((const float4*)W2)[(size_t)w * 64 + lane];
        float acc = w2.x * pv.x + w2.y * pv.y + w2.z * pv.z + w2.w * pv.w;
        acc = wave_reduce_add(acc);
        if (lane == 0) s_stats[w] = expf(acc + b2[w]);
    }
    __syncthreads();

    float alpha[MM], beta[MM], kappa[MM], cen[MM];
    #pragma unroll
    for (int m = 0; m < MM; ++m) {
        alpha[m] = s_stats[m];
        beta[m]  = s_stats[MM + m];
        kappa[m] = s_stats[2 * MM + m];
        cen[m]   = rintf(kappa[m]);   // round-half-even = jnp.round
    }

    // ---- Phase 2: dense p_ctx (exact reference math), global + LDS mirror ----
    float* pb = p_ctx + (size_t)b * LL;
    #pragma unroll
    for (int l = t; l < LL; l += 1024) {
        const float pos = (float)l;
        float p = 0.f;
        #pragma unroll
        for (int m = 0; m < MM; ++m) {
            if (pos >= cen[m] + (float)PRUNE_LEFT && pos < cen[m] + (float)(PRUNE_RIGHT + 1)) {
                const float diff = pos - kappa[m];
                p += alpha[m] * expf(-beta[m] * diff * diff);
            }
        }
        s_p[l] = p;
        pb[l] = p;
    }

    // ---- Window bounds (union of per-mixture prune windows, clamped) ----
    float cmin = 1e30f, cmax = -1e30f;
    #pragma unroll
    for (int m = 0; m < MM; ++m) {
        cmin = fminf(cmin, cen[m]);
        cmax = fmaxf(cmax, cen[m]);
    }
    const float lof = fminf(fmaxf(0.f, cmin + (float)PRUNE_LEFT), (float)LL);
    const float hif = fminf(fmaxf(0.f, cmax + (float)(PRUNE_RIGHT + 1)), (float)LL);
    const int lo = (int)lof;
    const int hi = ((int)hif < lo) ? lo : (int)hif;

    __syncthreads();   // s_p ready

    // ---- Phase 3: expected[b, d] over the window ----
    const int d  = t & 255;   // output column
    const int wq = t >> 8;    // row-quarter 0..3
    const float* cb = ctx + (size_t)b * LL * DD;

    float acc = 0.f;
    #pragma unroll 4
    for (int r = lo + wq; r < hi; r += 4) {
        acc += s_p[r] * cb[(size_t)r * DD + d];   // s_p broadcast; ctx coalesced
    }
    s_part[wq][d] = acc;
    __syncthreads();
    if (t < DD) {
        expected[(size_t)b * DD + t] =
            s_part[0][t] + s_part[1][t] + s_part[2][t] + s_part[3][t];
    }
}

extern "C" void kernel_launch(void* const* d_in, const int* in_sizes, int n_in,
                              void* d_out, int out_size, void* d_ws, size_t ws_size,
                              hipStream_t stream) {
    const float* ctx   = (const float*)d_in[0];
    const float* query = (const float*)d_in[1];
    const float* W1    = (const float*)d_in[2];
    const float* b1    = (const float*)d_in[3];
    const float* W2    = (const float*)d_in[4];
    const float* b2    = (const float*)d_in[5];

    float* out      = (float*)d_out;
    float* expected = out;             // (B, D)  = 8192 floats
    float* p_ctx    = out + BB * DD;   // (B, L)  = 262144 floats

    k_fused<<<BB, 1024, 0, stream>>>(ctx, query, W1, b1, W2, b2, expected, p_ctx);
}

// Round 5
// 16.034 us; speedup vs baseline: 2.8933x; 1.1147x over previous
//
#include <hip/hip_runtime.h>
#include <math.h>

// Problem dims (fixed by reference setup_inputs)
#define BB 32
#define LL 8192
#define DD 256
#define QQ 512
#define HH 256
#define MM 5
#define PRUNE_LEFT  (-50)
#define PRUNE_RIGHT (50)

__device__ inline float wave_reduce_add(float v) {
    #pragma unroll
    for (int m = 1; m < 64; m <<= 1)
        v += __shfl_xor(v, m, 64);
    return v;
}

// Kernel 1: proj = tanh(W1 @ q + b1), spread over 256 blocks.
// Block (c, b): rows h in [c*32, c*32+32), 4 waves x 8 rows each.
// Each block reads only 64 KB of W1 -> W1 stream is parallel across CUs.
__global__ void __launch_bounds__(256) k_proj(const float* __restrict__ query,
                                              const float* __restrict__ W1,
                                              const float* __restrict__ b1,
                                              float* __restrict__ proj_ws) {
    const int b    = blockIdx.y;
    const int c    = blockIdx.x;    // 0..7
    const int t    = threadIdx.x;
    const int lane = t & 63;
    const int w    = t >> 6;        // 0..3

    const float4* q4 = (const float4*)(query + (size_t)b * QQ);  // 128 float4
    const float4 qa = q4[lane];
    const float4 qb = q4[64 + lane];
    const float4* W1_4 = (const float4*)W1;   // row h = 128 float4

    #pragma unroll
    for (int r = 0; r < 8; ++r) {
        const int h = c * 32 + w * 8 + r;
        const float4 wa = W1_4[(size_t)h * 128 + lane];
        const float4 wb = W1_4[(size_t)h * 128 + 64 + lane];
        float acc = wa.x * qa.x + wa.y * qa.y + wa.z * qa.z + wa.w * qa.w
                  + wb.x * qb.x + wb.y * qb.y + wb.z * qb.z + wb.w * qb.w;
        acc = wave_reduce_add(acc);
        if (lane == 0) proj_ws[b * HH + h] = tanhf(acc + b1[h]);
    }
}

// Kernel 2: one block per batch, 1024 threads (16 waves).
//  - t=0..1023 issue a speculative warm prefetch of ctx rows [0,128) (held in
//    regs, consumed via asm keep-alive; correctness independent of the guess)
//  - stats = exp(W2 @ proj + b2), one row per wave (15 waves parallel)
//  - dense p_ctx[b,:] (exact reference math incl. prune mask) + LDS mirror
//  - expected[b,:] over the exact nonzero window, rows 4-way interleaved
__global__ void __launch_bounds__(1024, 1) k_fused(
    const float* __restrict__ ctx,
    const float* __restrict__ W2,
    const float* __restrict__ b2,
    const float* __restrict__ proj_ws,
    float* __restrict__ expected,
    float* __restrict__ p_ctx)
{
    __shared__ float s_stats[3 * MM];
    __shared__ float s_p[LL];          // 32 KB: this batch's p_ctx
    __shared__ float s_part[4][DD];

    const int b    = blockIdx.x;
    const int t    = threadIdx.x;
    const int lane = t & 63;
    const int w    = t >> 6;   // wave id 0..15

    // ---- Speculative prefetch: ctx rows [0,128) = 8192 float4, 8/thread ----
    const float4* cp = (const float4*)(ctx + (size_t)b * LL * DD);
    float4 pf[8];
    #pragma unroll
    for (int i = 0; i < 8; ++i) pf[i] = cp[(size_t)i * 1024 + t];

    // ---- stats = exp(W2 @ proj + b2), one row per wave ----
    if (w < 3 * MM) {
        const float4 pv = ((const float4*)(proj_ws + (size_t)b * HH))[lane];
        const float4 w2 = ((const float4*)W2)[(size_t)w * 64 + lane];
        float acc = w2.x * pv.x + w2.y * pv.y + w2.z * pv.z + w2.w * pv.w;
        acc = wave_reduce_add(acc);
        if (lane == 0) s_stats[w] = expf(acc + b2[w]);
    }
    __syncthreads();

    float alpha[MM], beta[MM], kappa[MM], cen[MM];
    #pragma unroll
    for (int m = 0; m < MM; ++m) {
        alpha[m] = s_stats[m];
        beta[m]  = s_stats[MM + m];
        kappa[m] = s_stats[2 * MM + m];
        cen[m]   = rintf(kappa[m]);   // round-half-even = jnp.round
    }

    // ---- dense p_ctx (exact reference math), global + LDS mirror ----
    float* pb = p_ctx + (size_t)b * LL;
    #pragma unroll
    for (int l = t; l < LL; l += 1024) {
        const float pos = (float)l;
        float p = 0.f;
        #pragma unroll
        for (int m = 0; m < MM; ++m) {
            if (pos >= cen[m] + (float)PRUNE_LEFT && pos < cen[m] + (float)(PRUNE_RIGHT + 1)) {
                const float diff = pos - kappa[m];
                p += alpha[m] * expf(-beta[m] * diff * diff);
            }
        }
        s_p[l] = p;
        pb[l] = p;
    }

    // ---- window bounds (union of per-mixture prune windows, clamped) ----
    float cmin = 1e30f, cmax = -1e30f;
    #pragma unroll
    for (int m = 0; m < MM; ++m) {
        cmin = fminf(cmin, cen[m]);
        cmax = fmaxf(cmax, cen[m]);
    }
    const float lof = fminf(fmaxf(0.f, cmin + (float)PRUNE_LEFT), (float)LL);
    const float hif = fminf(fmaxf(0.f, cmax + (float)(PRUNE_RIGHT + 1)), (float)LL);
    const int lo = (int)lof;
    const int hi = ((int)hif < lo) ? lo : (int)hif;

    // consume prefetch registers (keep loads alive without using results)
    {
        float keep = 0.f;
        #pragma unroll
        for (int i = 0; i < 8; ++i) keep += pf[i].x + pf[i].y + pf[i].z + pf[i].w;
        asm volatile("" :: "v"(keep));
    }

    __syncthreads();   // s_p ready

    // ---- expected[b, d] over the window ----
    const int d  = t & 255;   // output column
    const int wq = t >> 8;    // row-quarter 0..3
    const float* cb = ctx + (size_t)b * LL * DD;

    float acc = 0.f;
    #pragma unroll 4
    for (int r = lo + wq; r < hi; r += 4) {
        acc += s_p[r] * cb[(size_t)r * DD + d];   // s_p broadcast; ctx coalesced (L1/L2-warm)
    }
    s_part[wq][d] = acc;
    __syncthreads();
    if (t < DD) {
        expected[(size_t)b * DD + t] =
            s_part[0][t] + s_part[1][t] + s_part[2][t] + s_part[3][t];
    }
}

extern "C" void kernel_launch(void* const* d_in, const int* in_sizes, int n_in,
                              void* d_out, int out_size, void* d_ws, size_t ws_size,
                              hipStream_t stream) {
    const float* ctx   = (const float*)d_in[0];
    const float* query = (const float*)d_in[1];
    const float* W1    = (const float*)d_in[2];
    const float* b1    = (const float*)d_in[3];
    const float* W2    = (const float*)d_in[4];
    const float* b2    = (const float*)d_in[5];

    float* out      = (float*)d_out;
    float* expected = out;             // (B, D)  = 8192 floats
    float* p_ctx    = out + BB * DD;   // (B, L)  = 262144 floats
    float* proj_ws  = (float*)d_ws;    // (B, H)  = 8192 floats

    dim3 g1(8, BB);
    k_proj<<<g1, 256, 0, stream>>>(query, W1, b1, proj_ws);

    k_fused<<<BB, 1024, 0, stream>>>(ctx, W2, b2, proj_ws, expected, p_ctx);
}